// Round 3
// baseline (80.903 us; speedup 1.0000x reference)
//
#include <hip/hip_runtime.h>
#include <math.h>

#define LDIM 64
#define WAVES 4
#define QT 4      // queries per block tile
#define SEG 2     // obs-range segments per query tile
#define LOG2E 1.4426950408889634f

static __device__ __forceinline__ float fast_exp2(float x) {
#if __has_builtin(__builtin_amdgcn_exp2f)
    return __builtin_amdgcn_exp2f(x);
#else
    return exp2f(x);
#endif
}

// Precompute (padded to NoA = No rounded up to 64):
//   Bi[c][g][o] = float4{ B[4g+j][o] }, B[l][o] = b1[l] + sum_p pos_obs[o,p]*(W1[3+p,l]-W1[6+p,l])
//   V[o][l]     = bv[l] + sum_k h_obs[o,k]*Wv[k,l]
//   P4[o]       = (x, y, z, mask ? float(obs_batch+1) : 0)
__global__ __launch_bounds__(256) void gano_pre(
    const float* __restrict__ h_obs, const float* __restrict__ pos_obs,
    const float* __restrict__ W1, const float* __restrict__ b1,
    const float* __restrict__ Wv, const float* __restrict__ bv,
    const int* __restrict__ obs_mask, const int* __restrict__ obs_batch,
    float4* __restrict__ Bi, float* __restrict__ V, float4* __restrict__ P4,
    int No, int NoA)
{
    int gid = blockIdx.x * blockDim.x + threadIdx.x;
    if (gid >= NoA * LDIM) return;

    // --- V (row-major: gid = o*64 + l) ---
    {
        int o = gid >> 6;
        int l = gid & 63;
        float vv = 0.0f;
        if (o < No) {
            vv = bv[l];
            #pragma unroll 8
            for (int k = 0; k < LDIM; ++k)
                vv = fmaf(h_obs[o * LDIM + k], Wv[k * LDIM + l], vv);
        }
        V[gid] = vv;
    }
    // --- Bi: one float4 (4 consecutive l) per thread, gid < NoA*16 ---
    if (gid < NoA * 16) {
        int o = gid & 63;
        int g = (gid >> 6) & 15;
        int c = gid >> 10;
        int oo = (c << 6) + o;
        float4 r = make_float4(0.f, 0.f, 0.f, 0.f);
        if (oo < No) {
            float px = pos_obs[oo * 3 + 0], py = pos_obs[oo * 3 + 1], pz = pos_obs[oo * 3 + 2];
            float* rr = (float*)&r;
            #pragma unroll
            for (int j = 0; j < 4; ++j) {
                int l = 4 * g + j;
                float bb = b1[l];
                bb = fmaf(px, W1[3 * LDIM + l] - W1[6 * LDIM + l], bb);
                bb = fmaf(py, W1[4 * LDIM + l] - W1[7 * LDIM + l], bb);
                bb = fmaf(pz, W1[5 * LDIM + l] - W1[8 * LDIM + l], bb);
                rr[j] = bb;
            }
        }
        Bi[gid] = r;
    }
    // --- P4 ---
    if (gid < NoA) {
        float4 pp = make_float4(0.f, 0.f, 0.f, 0.f);
        if (gid < No)
            pp = make_float4(pos_obs[gid * 3 + 0], pos_obs[gid * 3 + 1], pos_obs[gid * 3 + 2],
                             obs_mask[gid] ? (float)(obs_batch[gid] + 1) : 0.0f);
        P4[gid] = pp;
    }
}

// Block = 4 queries x 1 segment. 4 waves stride 64-obs chunks of the union
// batch range. Logit phase: lane = obs, 4 queries per pass, B via float4.
// PV phase: lane = hidden dim, e broadcast via b128. Log2-domain softmax.
// Writes per-(query,seg) partials (m, denom, acc[64]) to ws.
__global__ __launch_bounds__(256) void gano_main(
    const float* __restrict__ pos_query, const float* __restrict__ W1,
    const float* __restrict__ W2,
    const float4* __restrict__ Bi, const float* __restrict__ V,
    const float4* __restrict__ P4,
    const int* __restrict__ obs_batch, const int* __restrict__ query_batch,
    float* __restrict__ partM, float* __restrict__ partD, float* __restrict__ partA,
    int No)
{
    const int qb   = blockIdx.x >> 1;
    const int seg  = blockIdx.x & 1;
    const int q0   = qb * QT;
    const int tid  = threadIdx.x;
    const int lane = tid & 63;
    const int wid  = tid >> 6;

    __shared__ float4 AWq[16][QT];        // a[q][4g..4g+3]
    __shared__ float4 W2L4[16];           // w2[4g..4g+3] * log2e
    __shared__ float4 e_t[WAVES][LDIM];   // per-wave e, 4 queries packed
    __shared__ float  s_m[WAVES][QT], s_d[WAVES][QT];
    __shared__ float  s_acc[WAVES][QT][LDIM];

    // Per-l query-side preact a[q][l] and scaled w2, scattered into LDS.
    if (tid < LDIM) {
        const int l = tid;
        float w0 = W1[0 * LDIM + l] + W1[6 * LDIM + l];
        float w1 = W1[1 * LDIM + l] + W1[7 * LDIM + l];
        float w2c = W1[2 * LDIM + l] + W1[8 * LDIM + l];
        #pragma unroll
        for (int q = 0; q < QT; ++q) {
            float a = pos_query[(q0 + q) * 3 + 0] * w0;
            a = fmaf(pos_query[(q0 + q) * 3 + 1], w1, a);
            a = fmaf(pos_query[(q0 + q) * 3 + 2], w2c, a);
            ((float*)&AWq[l >> 2][q])[l & 3] = a;
        }
        ((float*)&W2L4[l >> 2])[l & 3] = W2[l] * LOG2E;
    }

    // Union batch range for the query tile (both arrays sorted).
    const int b_lo = query_batch[q0];
    const int b_hi = query_batch[q0 + QT - 1];
    int lo = 0, hi = No;
    while (lo < hi) { int mid = (lo + hi) >> 1; if (obs_batch[mid] < b_lo) lo = mid + 1; else hi = mid; }
    const int start = lo;
    hi = No;
    while (lo < hi) { int mid = (lo + hi) >> 1; if (obs_batch[mid] < b_hi + 1) lo = mid + 1; else hi = mid; }
    const int end = lo;

    float pqx[QT], pqy[QT], pqz[QT], bqf[QT];
    #pragma unroll
    for (int q = 0; q < QT; ++q) {
        pqx[q] = pos_query[(q0 + q) * 3 + 0];
        pqy[q] = pos_query[(q0 + q) * 3 + 1];
        pqz[q] = pos_query[(q0 + q) * 3 + 2];
        bqf[q] = (float)(query_batch[q0 + q] + 1);
    }
    __syncthreads();

    float m[QT], dden[QT], acc[QT];
    #pragma unroll
    for (int q = 0; q < QT; ++q) { m[q] = -INFINITY; dden[q] = 0.0f; acc[q] = 0.0f; }

    if (end > start) {
        const int c0 = start >> 6;
        const int c1 = (end - 1) >> 6;
        const int nc = c1 - c0 + 1;
        const int n0 = (nc + 1) >> 1;
        const int cs = (seg == 0) ? c0 : c0 + n0;
        const int ce = (seg == 0) ? c0 + n0 : c1 + 1;

        for (int c = cs + wid; c < ce; c += WAVES) {
            const int o = (c << 6) + lane;
            const float4 p = P4[o];

            // ---- logit phase: lane = obs ----
            const float4* Bc = Bi + ((size_t)c << 10) + lane;
            float lg[QT];
            #pragma unroll
            for (int q = 0; q < QT; ++q) lg[q] = 0.0f;

            #pragma unroll
            for (int g = 0; g < 16; ++g) {
                const float4 Bv = Bc[g * 64];
                const float4 w2 = W2L4[g];
                #pragma unroll
                for (int q = 0; q < QT; ++q) {
                    const float4 a = AWq[g][q];
                    float t;
                    t = fmaxf(a.x + Bv.x, 0.0f); lg[q] = fmaf(t, w2.x, lg[q]);
                    t = fmaxf(a.y + Bv.y, 0.0f); lg[q] = fmaf(t, w2.y, lg[q]);
                    t = fmaxf(a.z + Bv.z, 0.0f); lg[q] = fmaf(t, w2.z, lg[q]);
                    t = fmaxf(a.w + Bv.w, 0.0f); lg[q] = fmaf(t, w2.w, lg[q]);
                }
            }

            // ---- mask + online softmax update per query ----
            float e_[QT];
            bool any = false;
            #pragma unroll
            for (int q = 0; q < QT; ++q) {
                const float dx = pqx[q] - p.x, dy = pqy[q] - p.y, dz = pqz[q] - p.z;
                const float d2 = fmaf(dz, dz, fmaf(dy, dy, dx * dx));
                const bool valid = (p.w == bqf[q]) & (d2 <= 1.0f);
                float lgq = valid ? lg[q] : -INFINITY;
                float cm = lgq;
                #pragma unroll
                for (int msk = 32; msk; msk >>= 1) cm = fmaxf(cm, __shfl_xor(cm, msk, 64));
                float e = 0.0f;
                if (cm > -INFINITY) {  // wave-uniform
                    const float nm = fmaxf(m[q], cm);
                    const float sc = fast_exp2(m[q] - nm);
                    m[q] = nm;
                    e = fast_exp2(lgq - nm);
                    dden[q] = fmaf(dden[q], sc, e);
                    acc[q] *= sc;
                    any = true;
                }
                e_[q] = e;
            }

            // ---- PV phase: lane = hidden dim ----
            if (any) {
                e_t[wid][lane] = make_float4(e_[0], e_[1], e_[2], e_[3]);
                const float* Vc = V + ((size_t)c << 12) + lane;
                #pragma unroll 16
                for (int o2 = 0; o2 < LDIM; ++o2) {
                    const float vv = Vc[o2 * 64];
                    const float4 e4 = e_t[wid][o2];
                    acc[0] = fmaf(e4.x, vv, acc[0]);
                    acc[1] = fmaf(e4.y, vv, acc[1]);
                    acc[2] = fmaf(e4.z, vv, acc[2]);
                    acc[3] = fmaf(e4.w, vv, acc[3]);
                }
            }
        }
    }

    // per-wave: reduce denom partials (obs-slot layout) over lanes
    #pragma unroll
    for (int q = 0; q < QT; ++q) {
        float d = dden[q];
        #pragma unroll
        for (int msk = 32; msk; msk >>= 1) d += __shfl_xor(d, msk, 64);
        dden[q] = d;
    }

    if (lane == 0) {
        #pragma unroll
        for (int q = 0; q < QT; ++q) { s_m[wid][q] = m[q]; s_d[wid][q] = dden[q]; }
    }
    #pragma unroll
    for (int q = 0; q < QT; ++q) s_acc[wid][q][lane] = acc[q];
    __syncthreads();

    if (wid == 0) {
        #pragma unroll
        for (int q = 0; q < QT; ++q) {
            float M = s_m[0][q];
            #pragma unroll
            for (int w = 1; w < WAVES; ++w) M = fmaxf(M, s_m[w][q]);
            float D = 0.0f, A = 0.0f;
            #pragma unroll
            for (int w = 0; w < WAVES; ++w) {
                const float sc = (s_m[w][q] == -INFINITY) ? 0.0f : fast_exp2(s_m[w][q] - M);
                D = fmaf(s_d[w][q], sc, D);
                A = fmaf(s_acc[w][q][lane], sc, A);
            }
            const int idx = (q0 + q) * SEG + seg;
            if (lane == 0) { partM[idx] = M; partD[idx] = D; }
            partA[idx * LDIM + lane] = A;
        }
    }
}

// Combine SEG partials per query. One wave per query.
__global__ __launch_bounds__(256) void gano_merge(
    const float* __restrict__ partM, const float* __restrict__ partD,
    const float* __restrict__ partA, float* __restrict__ out, int Nq)
{
    const int tid  = threadIdx.x;
    const int lane = tid & 63;
    const int wid  = tid >> 6;
    const int q    = blockIdx.x * WAVES + wid;
    if (q >= Nq) return;

    const float m0 = partM[q * SEG + 0];
    const float m1 = partM[q * SEG + 1];
    const float M  = fmaxf(m0, m1);
    float r = 0.0f;
    if (M > -INFINITY) {
        const float sc0 = (m0 == -INFINITY) ? 0.0f : fast_exp2(m0 - M);
        const float sc1 = (m1 == -INFINITY) ? 0.0f : fast_exp2(m1 - M);
        const float D = partD[q * SEG + 0] * sc0 + partD[q * SEG + 1] * sc1;
        const float A = partA[(q * SEG + 0) * LDIM + lane] * sc0 +
                        partA[(q * SEG + 1) * LDIM + lane] * sc1;
        r = A / fmaxf(D, 1e-30f);
    }
    out[q * LDIM + lane] = r;
}

extern "C" void kernel_launch(void* const* d_in, const int* in_sizes, int n_in,
                              void* d_out, int out_size, void* d_ws, size_t ws_size,
                              hipStream_t stream) {
    const float* h_obs     = (const float*)d_in[0];
    const float* pos_obs   = (const float*)d_in[1];
    const float* pos_query = (const float*)d_in[2];
    const float* W1        = (const float*)d_in[3];
    const float* b1        = (const float*)d_in[4];
    const float* W2        = (const float*)d_in[5];
    // d_in[6] = b2: constant shift, cancels in softmax -> unused
    const float* Wv        = (const float*)d_in[7];
    const float* bv        = (const float*)d_in[8];
    const int* obs_mask    = (const int*)d_in[9];
    const int* obs_batch   = (const int*)d_in[10];
    const int* query_batch = (const int*)d_in[11];

    const int No  = in_sizes[1] / 3;
    const int Nq  = in_sizes[2] / 3;
    const int NoA = (No + 63) & ~63;

    float4* Bi   = (float4*)d_ws;                          // NoA*16 float4
    float*  V    = (float*)(Bi + (size_t)NoA * 16);        // NoA*64 floats
    float4* P4   = (float4*)(V + (size_t)NoA * LDIM);      // NoA float4
    float*  partM = (float*)(P4 + NoA);                    // Nq*SEG
    float*  partD = partM + (size_t)Nq * SEG;              // Nq*SEG
    float*  partA = partD + (size_t)Nq * SEG;              // Nq*SEG*64

    const int pre_threads = 256;
    const int pre_blocks  = (NoA * LDIM + pre_threads - 1) / pre_threads;
    gano_pre<<<pre_blocks, pre_threads, 0, stream>>>(h_obs, pos_obs, W1, b1, Wv, bv,
                                                     obs_mask, obs_batch, Bi, V, P4, No, NoA);

    const int main_blocks = (Nq / QT) * SEG;
    gano_main<<<main_blocks, 256, 0, stream>>>(pos_query, W1, W2, Bi, V, P4,
                                               obs_batch, query_batch,
                                               partM, partD, partA, No);

    const int merge_blocks = (Nq + WAVES - 1) / WAVES;
    gano_merge<<<merge_blocks, 256, 0, stream>>>(partM, partD, partA, (float*)d_out, Nq);
}

// Round 4
// 31.866 us; speedup vs baseline: 2.5388x; 2.5388x over previous
//
#include <hip/hip_runtime.h>
#include <math.h>

#define LDIM 64
#define QT2 32   // queries per logits tile
#define QW 8     // queries per wave in logits kernel
#define QT3 4    // queries per pv block
#define SEG 4    // obs segments per pv query-group
#define LOG2E 1.4426950408889634f

static __device__ __forceinline__ float fast_exp2(float x) {
#if __has_builtin(__builtin_amdgcn_exp2f)
    return __builtin_amdgcn_exp2f(x);
#else
    return exp2f(x);
#endif
}

// K1: precompute everything reusable.
//   Bi[c][g][o] = float4{ B[4g+j][o] },  B[l][o] = b1[l] + pos_obs[o]·(W1[3:6,l]-W1[6:9,l])
//   V[o][l]     = bv[l] + h_obs[o]·Wv[:,l]
//   A[q][l]     = pos_query[q]·(W1[0:3,l]+W1[6:9,l])
//   P4[o]       = (x,y,z, mask ? batch+1 : 0)
//   w2s[l]      = W2[l]*log2e
//   qrange[q]   = [start,end) of q's batch in obs_batch (sorted)
__global__ __launch_bounds__(256) void gano_pre(
    const float* __restrict__ h_obs, const float* __restrict__ pos_obs,
    const float* __restrict__ pos_query,
    const float* __restrict__ W1, const float* __restrict__ b1,
    const float* __restrict__ W2,
    const float* __restrict__ Wv, const float* __restrict__ bv,
    const int* __restrict__ obs_mask, const int* __restrict__ obs_batch,
    const int* __restrict__ query_batch,
    float4* __restrict__ Bi, float4* __restrict__ P4,
    float* __restrict__ V, float* __restrict__ A, float* __restrict__ w2s,
    int2* __restrict__ qrange,
    int No, int NoA, int Nq)
{
    const int gid = blockIdx.x * blockDim.x + threadIdx.x;
    if (gid >= NoA * LDIM) return;
    // V[o][l]
    {
        const int o = gid >> 6, l = gid & 63;
        float vv = 0.0f;
        if (o < No) {
            vv = bv[l];
            #pragma unroll 8
            for (int k = 0; k < LDIM; ++k)
                vv = fmaf(h_obs[o * LDIM + k], Wv[k * LDIM + l], vv);
        }
        V[gid] = vv;
    }
    // Bi[c][g][o]
    if (gid < NoA * 16) {
        const int o = gid & 63, g = (gid >> 6) & 15, c = gid >> 10;
        const int oo = (c << 6) + o;
        float4 r = make_float4(0.f, 0.f, 0.f, 0.f);
        if (oo < No) {
            const float px = pos_obs[oo*3+0], py = pos_obs[oo*3+1], pz = pos_obs[oo*3+2];
            float* rr = (float*)&r;
            #pragma unroll
            for (int j = 0; j < 4; ++j) {
                const int l = 4 * g + j;
                float bb = b1[l];
                bb = fmaf(px, W1[3*LDIM+l] - W1[6*LDIM+l], bb);
                bb = fmaf(py, W1[4*LDIM+l] - W1[7*LDIM+l], bb);
                bb = fmaf(pz, W1[5*LDIM+l] - W1[8*LDIM+l], bb);
                rr[j] = bb;
            }
        }
        Bi[gid] = r;
    }
    // A[q][l]
    if (gid < Nq * LDIM) {
        const int q = gid >> 6, l = gid & 63;
        float a = pos_query[q*3+0] * (W1[0*LDIM+l] + W1[6*LDIM+l]);
        a = fmaf(pos_query[q*3+1], W1[1*LDIM+l] + W1[7*LDIM+l], a);
        a = fmaf(pos_query[q*3+2], W1[2*LDIM+l] + W1[8*LDIM+l], a);
        A[gid] = a;
    }
    if (gid < LDIM) w2s[gid] = W2[gid] * LOG2E;
    // P4[o]
    if (gid < NoA) {
        float4 pp = make_float4(0.f, 0.f, 0.f, 0.f);
        if (gid < No)
            pp = make_float4(pos_obs[gid*3+0], pos_obs[gid*3+1], pos_obs[gid*3+2],
                             obs_mask[gid] ? (float)(obs_batch[gid] + 1) : 0.0f);
        P4[gid] = pp;
    }
    // qrange[q]
    if (gid < Nq) {
        const int b = query_batch[gid];
        int lo = 0, hi = No;
        while (lo < hi) { int mid = (lo + hi) >> 1; if (obs_batch[mid] < b) lo = mid + 1; else hi = mid; }
        const int s = lo;
        hi = No;
        while (lo < hi) { int mid = (lo + hi) >> 1; if (obs_batch[mid] < b + 1) lo = mid + 1; else hi = mid; }
        qrange[gid] = make_int2(s, lo);
    }
}

// K2: masked logits (log2-scaled) for a 32-query tile x 64-obs chunk.
// Wave = 8 queries. Pure fma/fmax stream, no cross-lane ops.
// Writes lg[q][o] = logit*log2e or -inf, for every chunk intersecting the
// tile's batch span. (Entries of non-intersecting chunks are never read.)
__global__ __launch_bounds__(256) void gano_logits(
    const float4* __restrict__ Bi, const float4* __restrict__ P4,
    const float* __restrict__ A, const float* __restrict__ w2s,
    const float* __restrict__ pos_query,
    const int* __restrict__ obs_batch, const int* __restrict__ query_batch,
    float* __restrict__ lg, int No, int NoA)
{
    const int c  = blockIdx.x;
    const int q0 = blockIdx.y * QT2;
    if ((c << 6) >= No) return;
    // batch-span intersection early-exit (both arrays sorted)
    const int c_lo = obs_batch[c << 6];
    const int c_hi = obs_batch[min((c << 6) + 63, No - 1)];
    const int t_lo = query_batch[q0];
    const int t_hi = query_batch[q0 + QT2 - 1];
    if (c_lo > t_hi || c_hi < t_lo) return;

    __shared__ float4 a4[QT2][16];
    __shared__ float4 w2_4[16];
    __shared__ float4 qp4[QT2];

    const int tid = threadIdx.x;
    for (int i = tid; i < QT2 * 16; i += 256)
        a4[i >> 4][i & 15] = ((const float4*)A)[((size_t)(q0 + (i >> 4)) << 4) + (i & 15)];
    if (tid < 16) w2_4[tid] = ((const float4*)w2s)[tid];
    if (tid < QT2) {
        const int q = q0 + tid;
        qp4[tid] = make_float4(pos_query[q*3+0], pos_query[q*3+1], pos_query[q*3+2],
                               (float)(query_batch[q] + 1));
    }
    __syncthreads();

    const int lane = tid & 63, wid = tid >> 6;
    const float4 p = P4[(c << 6) + lane];
    const float4* Bc = Bi + ((size_t)c << 10) + lane;

    float lgq[QW];
    #pragma unroll
    for (int j = 0; j < QW; ++j) lgq[j] = 0.0f;

    #pragma unroll
    for (int g = 0; g < 16; ++g) {
        const float4 Bv = Bc[g << 6];
        const float4 w  = w2_4[g];
        #pragma unroll
        for (int j = 0; j < QW; ++j) {
            const float4 a = a4[wid * QW + j][g];
            lgq[j] = fmaf(fmaxf(a.x + Bv.x, 0.f), w.x, lgq[j]);
            lgq[j] = fmaf(fmaxf(a.y + Bv.y, 0.f), w.y, lgq[j]);
            lgq[j] = fmaf(fmaxf(a.z + Bv.z, 0.f), w.z, lgq[j]);
            lgq[j] = fmaf(fmaxf(a.w + Bv.w, 0.f), w.w, lgq[j]);
        }
    }

    float* lrow = lg + (size_t)(q0 + wid * QW) * NoA + (c << 6) + lane;
    #pragma unroll
    for (int j = 0; j < QW; ++j) {
        const float4 qp = qp4[wid * QW + j];
        const float dx = qp.x - p.x, dy = qp.y - p.y, dz = qp.z - p.z;
        const float d2 = fmaf(dz, dz, fmaf(dy, dy, dx * dx));
        const bool valid = (p.w == qp.w) & (d2 <= 1.0f);
        lrow[(size_t)j * NoA] = valid ? lgq[j] : -INFINITY;
    }
}

// K3: per 4-query group x segment: (1) per-query M,D over its own range
// (vectorized, one shfl-reduce pair per QUERY), (2) PV over segment chunks
// with e from LDS broadcast; no rescale chains, no barriers in the loop.
// Writes D-normalized partial outputs.
__global__ __launch_bounds__(256) void gano_pv(
    const float* __restrict__ lg, const float* __restrict__ V,
    const int2* __restrict__ qrange,
    float* __restrict__ partA, int NoA)
{
    const int grp = blockIdx.x >> 2;
    const int seg = blockIdx.x & 3;
    const int q0  = grp * QT3;
    const int tid = threadIdx.x, lane = tid & 63, wid = tid >> 6;

    __shared__ float sM[QT3], sD[QT3];
    __shared__ float4 e4[4][LDIM];
    __shared__ float sacc[4][QT3][LDIM];

    // phase 1: wave `wid` -> query q0+wid
    {
        const int q = q0 + wid;
        const int2 r = qrange[q];
        const float* row = lg + (size_t)q * NoA;
        float mx = -INFINITY;
        for (int o = r.x + lane; o < r.y; o += 64) mx = fmaxf(mx, row[o]);
        #pragma unroll
        for (int m = 32; m; m >>= 1) mx = fmaxf(mx, __shfl_xor(mx, m, 64));
        const float Mq = (mx == -INFINITY) ? 0.0f : mx;  // avoids inf-inf NaN
        float sum = 0.0f;
        for (int o = r.x + lane; o < r.y; o += 64) sum += fast_exp2(row[o] - Mq);
        #pragma unroll
        for (int m = 32; m; m >>= 1) sum += __shfl_xor(sum, m, 64);
        if (lane == 0) { sM[wid] = Mq; sD[wid] = sum; }
    }
    __syncthreads();

    const float M0 = sM[0], M1 = sM[1], M2 = sM[2], M3 = sM[3];
    float acc0 = 0.f, acc1 = 0.f, acc2 = 0.f, acc3 = 0.f;

    const int s4 = qrange[q0].x;
    const int e4u = qrange[q0 + QT3 - 1].y;
    if (e4u > s4) {
        const int c0 = s4 >> 6, c1 = (e4u - 1) >> 6;
        const int nc = c1 - c0 + 1;
        const int cs = c0 + (nc * seg) / SEG;
        const int ce = c0 + (nc * (seg + 1)) / SEG;
        const float* r0 = lg + (size_t)(q0 + 0) * NoA;
        const float* r1 = lg + (size_t)(q0 + 1) * NoA;
        const float* r2 = lg + (size_t)(q0 + 2) * NoA;
        const float* r3 = lg + (size_t)(q0 + 3) * NoA;
        for (int c = cs + wid; c < ce; c += 4) {
            const int o = (c << 6) + lane;
            float4 ev;
            ev.x = fast_exp2(r0[o] - M0);   // -inf rows -> 0
            ev.y = fast_exp2(r1[o] - M1);
            ev.z = fast_exp2(r2[o] - M2);
            ev.w = fast_exp2(r3[o] - M3);
            e4[wid][lane] = ev;
            const float* Vc = V + ((size_t)c << 12) + lane;
            #pragma unroll
            for (int oo = 0; oo < LDIM; ++oo) {
                const float4 e = e4[wid][oo];   // b128 broadcast
                const float vv = Vc[oo << 6];   // coalesced 256B line
                acc0 = fmaf(e.x, vv, acc0);
                acc1 = fmaf(e.y, vv, acc1);
                acc2 = fmaf(e.z, vv, acc2);
                acc3 = fmaf(e.w, vv, acc3);
            }
        }
    }

    sacc[wid][0][lane] = acc0;
    sacc[wid][1][lane] = acc1;
    sacc[wid][2][lane] = acc2;
    sacc[wid][3][lane] = acc3;
    __syncthreads();

    {
        const int q = wid;
        const float a = (sacc[0][q][lane] + sacc[1][q][lane]) +
                        (sacc[2][q][lane] + sacc[3][q][lane]);
        const float rd = 1.0f / fmaxf(sD[q], 1e-30f);
        partA[(((size_t)(q0 + q)) * SEG + seg) * LDIM + lane] = a * rd;
    }
}

// K4: sum segment partials.
__global__ __launch_bounds__(256) void gano_merge(
    const float* __restrict__ partA, float* __restrict__ out, int n)
{
    const int gid = blockIdx.x * blockDim.x + threadIdx.x;
    if (gid >= n) return;
    const int q = gid >> 6, l = gid & 63;
    const float* p = partA + ((size_t)q * SEG) * LDIM + l;
    out[gid] = (p[0] + p[LDIM]) + (p[2 * LDIM] + p[3 * LDIM]);
}

extern "C" void kernel_launch(void* const* d_in, const int* in_sizes, int n_in,
                              void* d_out, int out_size, void* d_ws, size_t ws_size,
                              hipStream_t stream) {
    const float* h_obs     = (const float*)d_in[0];
    const float* pos_obs   = (const float*)d_in[1];
    const float* pos_query = (const float*)d_in[2];
    const float* W1        = (const float*)d_in[3];
    const float* b1        = (const float*)d_in[4];
    const float* W2        = (const float*)d_in[5];
    // d_in[6] = b2: constant shift, cancels in softmax -> unused
    const float* Wv        = (const float*)d_in[7];
    const float* bv        = (const float*)d_in[8];
    const int* obs_mask    = (const int*)d_in[9];
    const int* obs_batch   = (const int*)d_in[10];
    const int* query_batch = (const int*)d_in[11];

    const int No  = in_sizes[1] / 3;
    const int Nq  = in_sizes[2] / 3;
    const int NoA = (No + 63) & ~63;
    const int nChunks = NoA / 64;

    // ws layout (assumes ws_size >= ~11 MB for Nq=1024, No=2048)
    float4* Bi  = (float4*)d_ws;                        // NoA*16 float4
    float4* P4  = Bi + (size_t)NoA * 16;                // NoA float4
    float*  V   = (float*)(P4 + NoA);                   // NoA*64 f
    float*  A   = V + (size_t)NoA * LDIM;               // Nq*64 f
    float*  w2s = A + (size_t)Nq * LDIM;                // 64 f
    int2*   qr  = (int2*)(w2s + LDIM);                  // Nq int2
    float*  lgb = (float*)(qr + Nq);                    // Nq*NoA f
    float*  pA  = lgb + (size_t)Nq * NoA;               // Nq*SEG*64 f

    gano_pre<<<(NoA * LDIM + 255) / 256, 256, 0, stream>>>(
        h_obs, pos_obs, pos_query, W1, b1, W2, Wv, bv,
        obs_mask, obs_batch, query_batch,
        Bi, P4, V, A, w2s, qr, No, NoA, Nq);

    dim3 g2(nChunks, Nq / QT2);
    gano_logits<<<g2, 256, 0, stream>>>(Bi, P4, A, w2s, pos_query,
                                        obs_batch, query_batch, lgb, No, NoA);

    gano_pv<<<(Nq / QT3) * SEG, 256, 0, stream>>>(lgb, V, qr, pA, NoA);

    gano_merge<<<(Nq * LDIM + 255) / 256, 256, 0, stream>>>(pA, (float*)d_out, Nq * LDIM);
}